// Round 6
// baseline (200.606 us; speedup 1.0000x reference)
//
#include <hip/hip_runtime.h>

// OHEM loss - round 6: return to the empirically-fastest R1 skeleton
// (rolled loop, fire-and-forget LDS atomics -> no loop-carried deps,
// compiler streams loads) with only targeted fixes:
//   - u32 count-only LDS histogram binned on |d| (uniform -> no same-address
//     pile-up; u32 -> single-bank atomics). Reconstruction from midpoint^2
//     (proven absmax=0 in round 3).
//   - positives kept exact in registers, one packed u64 global atomic/wave.
//   - 2048 blocks x 1024 thr (2 float4-pairs per thread): continuous block
//     stream keeps CUs in load-issue phase (latency/MLP-bound regime).

#define NB 1024
#define BPL (NB / 64)            // bins per lane in select kernel
#define ROWSTRIDE 1040           // u32 stride per row (1024 bins + pad)
#define NPIX 262144              // 512*512
#define NROWS 64
#define BLK 1024
#define CPR 32                   // chunk-blocks per row -> 2048 blocks
#define CHUNK (NPIX / CPR)       // 8192 elems per block
#define ITERS (CHUNK / (BLK * 4))// 2 float4-pair iterations per thread
#define SCALE 1048576.0f         // 2^20 fixed point for positive sums
#define INV_SCALE (1.0 / 1048576.0)

__global__ __launch_bounds__(BLK)
void ohem_hist_kernel(const float* __restrict__ pred,
                      const float* __restrict__ region,
                      const float* __restrict__ affinity,
                      unsigned int* __restrict__ g_hist,
                      unsigned long long* __restrict__ g_pos)
{
    __shared__ unsigned int h[NB];
    const int row   = blockIdx.x >> 5;         // 0..63
    const int chunk = blockIdx.x & 31;
    const int b = row & 31;
    const int c = row >> 5;                    // 0: region, 1: affinity
    const float4* p4 = (const float4*)(pred + (size_t)(b * 2 + c) * NPIX
                                            + (size_t)chunk * CHUNK);
    const float4* s4 = (const float4*)((c == 0 ? region : affinity)
                                       + (size_t)b * NPIX + (size_t)chunk * CHUNK);

    h[threadIdx.x] = 0;                        // BLK == NB: one bin per thread
    __syncthreads();

    unsigned int poscnt = 0, possum = 0;       // exact positive accum

    #pragma unroll
    for (int it = 0; it < ITERS; ++it) {
        float4 pv = p4[it * BLK + threadIdx.x];
        float4 sv = s4[it * BLK + threadIdx.x];
        float pp[4] = {pv.x, pv.y, pv.z, pv.w};
        float ss[4] = {sv.x, sv.y, sv.z, sv.w};
        #pragma unroll
        for (int j = 0; j < 4; ++j) {
            float d  = pp[j] - ss[j];
            int bin = (int)(fabsf(d) * (float)NB);   // |d| < 1 always here
            if (bin > NB - 1) bin = NB - 1;
            bool pos = (ss[j] >= 0.1f);
            if (!pos) atomicAdd(&h[bin], 1u);  // uniform bins, u32: cheap
            poscnt += pos ? 1u : 0u;
            possum += pos ? (unsigned int)(d * d * SCALE + 0.5f) : 0u;
        }
    }

    // Per-wave reduce of positives: pack (cnt << 40) | fixedsum.
    // Per-lane fixedsum <= 8*2^20 = 2^23; wave sum <= 2^29 < 2^40.
    unsigned long long pp64 = ((unsigned long long)poscnt << 40)
                            | (unsigned long long)possum;
    #pragma unroll
    for (int off = 32; off > 0; off >>= 1) pp64 += __shfl_down(pp64, off);
    if ((threadIdx.x & 63) == 0 && pp64) atomicAdd(&g_pos[row], pp64);

    __syncthreads();
    unsigned int v = h[threadIdx.x];
    if (v) atomicAdd(&g_hist[(size_t)row * ROWSTRIDE + threadIdx.x], v);
}

__global__ __launch_bounds__(64)
void ohem_select_kernel(const unsigned int* __restrict__ g_hist,
                        const unsigned long long* __restrict__ g_pos,
                        float* __restrict__ row_result)
{
    const int row = blockIdx.x;
    const unsigned int* gh = g_hist + (size_t)row * ROWSTRIDE;
    const int t = threadIdx.x;   // single wave of 64

    // Lane t owns BPL consecutive bins counted FROM THE TOP (descending |d|).
    unsigned long long c_t = 0;
    double w_t = 0.0;            // sum of cnt * midpoint^2 (= sum of d^2)
    for (int j = 0; j < BPL; ++j) {
        int bin = NB - 1 - (t * BPL + j);
        unsigned int v = gh[bin];
        double m = ((double)bin + 0.5) / (double)NB;
        c_t += v;
        w_t += (double)v * m * m;
    }
    // Inclusive scan across the wave.
    unsigned long long ic = c_t; double iw = w_t;
    for (int off = 1; off < 64; off <<= 1) {
        unsigned long long uc = __shfl_up(ic, off);
        double             uw = __shfl_up(iw, off);
        if (t >= off) { ic += uc; iw += uw; }
    }
    unsigned long long pre_c = ic - c_t;      // exclusive prefix (from top)
    double pre_w = iw - w_t;

    unsigned long long pospack = g_pos[row];
    unsigned long long pc = pospack >> 40;
    double psum = (double)(pospack & ((1ULL << 40) - 1)) * INV_SCALE;
    long long negc = (long long)NPIX - (long long)pc;
    long long k;
    if (pc > 0) { k = 3LL * (long long)pc; if (k > negc) k = negc; }
    else        { k = 500; }                  // top-500-mean fallback

    if (pc > 0 && k == 0) {                   // all pixels positive: nega = -1
        if (t == 0) row_result[row] = (float)(psum / (double)pc - 1.0);
        return;
    }

    // Exactly one lane contains the k-th value crossing.
    if ((long long)pre_c < k && k <= (long long)(pre_c + c_t)) {
        unsigned long long cum = pre_c;
        double cw = pre_w;
        double nega = 0.0;
        for (int j = 0; j < BPL; ++j) {
            int bin = NB - 1 - (t * BPL + j);
            unsigned int v = gh[bin];
            double m = ((double)bin + 0.5) / (double)NB;
            if ((long long)(cum + v) >= k) {
                unsigned long long need = (unsigned long long)k - cum;
                nega = (cw + (double)need * m * m) / (double)k;
                break;
            }
            cum += v;
            cw  += (double)v * m * m;
        }
        double posi = (pc > 0) ? psum / (double)pc : 0.0;
        row_result[row] = (float)(posi + nega);
    }
}

__global__ void final_reduce_kernel(const float* __restrict__ row_result,
                                    float* __restrict__ out)
{
    float v = row_result[threadIdx.x];   // 64 lanes = 64 rows
    #pragma unroll
    for (int off = 32; off > 0; off >>= 1) v += __shfl_down(v, off);
    if (threadIdx.x == 0) out[0] = v * (1.0f / 32.0f);
}

extern "C" void kernel_launch(void* const* d_in, const int* in_sizes, int n_in,
                              void* d_out, int out_size, void* d_ws, size_t ws_size,
                              hipStream_t stream)
{
    const float* pred     = (const float*)d_in[0];
    const float* region   = (const float*)d_in[1];
    const float* affinity = (const float*)d_in[2];
    float* out = (float*)d_out;

    unsigned int* g_hist = (unsigned int*)d_ws;
    const size_t hist_bytes = (size_t)NROWS * ROWSTRIDE * sizeof(unsigned int);
    unsigned long long* g_pos = (unsigned long long*)((char*)d_ws + hist_bytes);
    float* row_result = (float*)((char*)d_ws + hist_bytes
                                 + NROWS * sizeof(unsigned long long));

    hipMemsetAsync(d_ws, 0,
                   hist_bytes + NROWS * sizeof(unsigned long long)
                 + NROWS * sizeof(float), stream);
    ohem_hist_kernel<<<NROWS * CPR, BLK, 0, stream>>>(pred, region, affinity,
                                                      g_hist, g_pos);
    ohem_select_kernel<<<NROWS, 64, 0, stream>>>(g_hist, g_pos, row_result);
    final_reduce_kernel<<<1, 64, 0, stream>>>(row_result, out);
}

// Round 7
// 44.550 us; speedup vs baseline: 4.5030x; 4.5030x over previous
//
#include <hip/hip_runtime.h>

// OHEM loss - round 7: R1's main loop VERBATIM (empirically fastest across
// 6 rounds: 512 blocks x 1024 thr x 8 consume-immediately float4 iterations,
// fire-and-forget u64 LDS atomics, zero loop-carried register deps).
// Only the surroundings change:
//  - merge phase: per-block private slice STORES (g_hist[chunk][row][bin])
//    instead of ~1M contended global atomic RMWs.
//  - no memset dispatch: slices fully overwritten each call; row_result
//    written exactly once per row by select (deterministic).
//  - select sums the 8 slices (exact integer adds, bit-identical math).

#define NB 2048
#define RSTR 2056                 // row stride in u64 (2048 bins + pos + pad)
#define CSTR ((size_t)64 * RSTR)  // chunk-slice stride in u64
#define NPIX 262144               // 512*512
#define NROWS 64
#define C_CHUNKS 8
#define BLK 1024
#define CHUNK (NPIX / C_CHUNKS)   // 32768 elems per block
#define ITERS (CHUNK / (BLK * 4)) // 8
#define SCALE 1048576.0f          // 2^20 fixed point
#define INV_SCALE (1.0 / 1048576.0)

__global__ __launch_bounds__(BLK)
void ohem_hist_kernel(const float* __restrict__ pred,
                      const float* __restrict__ region,
                      const float* __restrict__ affinity,
                      unsigned long long* __restrict__ g_hist)
{
    __shared__ unsigned long long h[NB + 1];
    const int row   = blockIdx.x / C_CHUNKS;   // 0..63
    const int chunk = blockIdx.x % C_CHUNKS;
    const int b = row & 31;
    const int c = row >> 5;                    // 0: region, 1: affinity
    const float* p = pred + (size_t)(b * 2 + c) * NPIX + (size_t)chunk * CHUNK;
    const float* s = (c == 0 ? region : affinity) + (size_t)b * NPIX + (size_t)chunk * CHUNK;

    for (int i = threadIdx.x; i <= NB; i += BLK) h[i] = 0;
    __syncthreads();

    const float4* p4 = (const float4*)p;
    const float4* s4 = (const float4*)s;
    #pragma unroll
    for (int it = 0; it < ITERS; ++it) {       // R1 main loop, byte-identical
        float4 pv = p4[it * BLK + threadIdx.x];
        float4 sv = s4[it * BLK + threadIdx.x];
        float pp[4]  = {pv.x, pv.y, pv.z, pv.w};
        float ssv[4] = {sv.x, sv.y, sv.z, sv.w};
        #pragma unroll
        for (int j = 0; j < 4; ++j) {
            float d = pp[j] - ssv[j];
            float x = d * d;                      // pre_loss, in [0,1]
            int bin;
            if (ssv[j] >= 0.1f) {
                bin = NB;                         // positive slot
            } else {
                bin = (int)(x * (float)NB);
                if (bin > NB - 1) bin = NB - 1;
            }
            unsigned long long packed =
                (1ULL << 40) | (unsigned long long)(x * SCALE + 0.5f);
            atomicAdd(&h[bin], packed);           // deterministic integer atomic
        }
    }
    __syncthreads();

    // Private-slice store (coalesced, no RMW, no contention).
    unsigned long long* gh = g_hist + (size_t)chunk * CSTR + (size_t)row * RSTR;
    gh[threadIdx.x]        = h[threadIdx.x];
    gh[threadIdx.x + 1024] = h[threadIdx.x + 1024];
    if (threadIdx.x == 0) gh[2048] = h[2048];
}

__global__ __launch_bounds__(64)
void ohem_select_kernel(const unsigned long long* __restrict__ g_hist,
                        float* __restrict__ row_result)
{
    const int row = blockIdx.x;
    const unsigned long long* gh = g_hist + (size_t)row * RSTR;
    const int t = threadIdx.x;   // single wave of 64
    const unsigned long long MASK = (1ULL << 40) - 1;

    // Lane t owns 32 consecutive bins FROM THE TOP; sum the 8 chunk slices.
    // Slice sums are exact: value fields <= 8*2^35 = 2^38 < 2^40 (no carry).
    unsigned long long c_t = 0, s_t = 0;
    for (int j = 0; j < 32; ++j) {
        int bin = NB - 1 - (t * 32 + j);
        unsigned long long v = 0;
        #pragma unroll
        for (int sl = 0; sl < C_CHUNKS; ++sl) v += gh[(size_t)sl * CSTR + bin];
        c_t += v >> 40;
        s_t += v & MASK;
    }
    // Inclusive scan across the wave (64-bit shuffles).
    unsigned long long ic = c_t, isum = s_t;
    for (int off = 1; off < 64; off <<= 1) {
        unsigned long long uc = __shfl_up(ic, off);
        unsigned long long us = __shfl_up(isum, off);
        if (t >= off) { ic += uc; isum += us; }
    }
    unsigned long long pre_c = ic - c_t;     // exclusive prefix (from top)
    unsigned long long pre_s = isum - s_t;

    unsigned long long pospack = 0;
    #pragma unroll
    for (int sl = 0; sl < C_CHUNKS; ++sl) pospack += gh[(size_t)sl * CSTR + NB];
    unsigned long long pc = pospack >> 40;
    double psum = (double)(pospack & MASK) * INV_SCALE;
    long long negc = (long long)NPIX - (long long)pc;
    long long k;
    if (pc > 0) { k = 3LL * (long long)pc; if (k > negc) k = negc; }
    else        { k = 500; }                  // top-500-mean fallback path

    if (pc > 0 && k == 0) {                   // all pixels positive: nega = -1
        if (t == 0) row_result[row] = (float)(psum / (double)pc - 1.0);
        return;
    }

    // Exactly one lane contains the k-th value crossing.
    if ((long long)pre_c < k && k <= (long long)(pre_c + c_t)) {
        unsigned long long cum = pre_c, cums = pre_s;
        double nega = 0.0;
        for (int j = 0; j < 32; ++j) {
            int bin = NB - 1 - (t * 32 + j);
            unsigned long long v = 0;
            #pragma unroll
            for (int sl = 0; sl < C_CHUNKS; ++sl) v += gh[(size_t)sl * CSTR + bin];
            unsigned long long cb = v >> 40, sb = v & MASK;
            if ((long long)(cum + cb) >= k) {
                unsigned long long need = (unsigned long long)k - cum;
                double avg = cb ? (double)sb / (double)cb : 0.0;
                nega = ((double)cums + (double)need * avg) * INV_SCALE / (double)k;
                break;
            }
            cum += cb; cums += sb;
        }
        double posi = (pc > 0) ? psum / (double)pc : 0.0;
        row_result[row] = (float)(posi + nega);
    }
}

__global__ void final_reduce_kernel(const float* __restrict__ row_result,
                                    float* __restrict__ out)
{
    float v = row_result[threadIdx.x];   // 64 lanes = 64 rows
    #pragma unroll
    for (int off = 32; off > 0; off >>= 1) v += __shfl_down(v, off);
    if (threadIdx.x == 0) out[0] = v * (1.0f / 32.0f);
}

extern "C" void kernel_launch(void* const* d_in, const int* in_sizes, int n_in,
                              void* d_out, int out_size, void* d_ws, size_t ws_size,
                              hipStream_t stream)
{
    const float* pred     = (const float*)d_in[0];
    const float* region   = (const float*)d_in[1];
    const float* affinity = (const float*)d_in[2];
    float* out = (float*)d_out;

    unsigned long long* g_hist = (unsigned long long*)d_ws;   // 8 slices
    const size_t hist_bytes = C_CHUNKS * CSTR * sizeof(unsigned long long);
    float* row_result = (float*)((char*)d_ws + hist_bytes);

    // No memset needed: hist slices fully overwritten; row_result fully
    // written (one write per row) by select every call.
    ohem_hist_kernel<<<NROWS * C_CHUNKS, BLK, 0, stream>>>(pred, region, affinity,
                                                           g_hist);
    ohem_select_kernel<<<NROWS, 64, 0, stream>>>(g_hist, row_result);
    final_reduce_kernel<<<1, 64, 0, stream>>>(row_result, out);
}